// Round 2
// baseline (379.910 us; speedup 1.0000x reference)
//
#include <hip/hip_runtime.h>
#include <hip/hip_bf16.h>

typedef __attribute__((ext_vector_type(8))) short s16x8;   // 8 bf16 (4 VGPRs)
typedef __attribute__((ext_vector_type(4))) float f32x4;
typedef unsigned short u16;
typedef unsigned int u32;

#define SDIM 2048
#define BDIM 2
#define HDIM 12
#define DDIM 64
#define EDIM 768
#define MDIM 4096          // S*B rows
#define SCALE_Q 0.125f     // D^-0.5
#define KSPLIT 1024        // keys per wave (2 waves split the 2048-key range)

static __device__ __forceinline__ f32x4 zero4() {
    f32x4 v; v[0] = v[1] = v[2] = v[3] = 0.f; return v;
}

// fp32 -> bf16 bits, round-to-nearest-even
static __device__ __forceinline__ u16 f2b(float x) {
    u32 u = __builtin_bit_cast(u32, x);
    u32 lsb = (u >> 16) & 1u;
    u += 0x7fffu + lsb;
    return (u16)(u >> 16);
}

static __device__ __forceinline__ f32x4 mfma16(s16x8 a, s16x8 b, f32x4 c) {
    return __builtin_amdgcn_mfma_f32_16x16x32_bf16(a, b, c, 0, 0, 0);
}

// ---------------------------------------------------------------------------
// key_padding_mask arrives with unknown storage (bool bytes / int32 / float32).
// Detect encoding (deterministic) and emit float poison: masked -> -1e30, else 0.
// ---------------------------------------------------------------------------
__global__ void mask_norm_kernel(const u32* __restrict__ raw, float* __restrict__ out) {
    __shared__ int okInt, okFloat;
    int t = threadIdx.x;
    if (t == 0) { okInt = 1; okFloat = 1; }
    __syncthreads();
    int li = 1, lf = 1;
    for (int i = t; i < 1024; i += blockDim.x) {
        u32 v = raw[i];
        if (v > 1u) li = 0;
        if (v != 0u && v != 0x3F800000u) lf = 0;
    }
    if (!li) atomicAnd(&okInt, 0);
    if (!lf) atomicAnd(&okFloat, 0);
    __syncthreads();
    const unsigned char* rb = (const unsigned char*)raw;
    for (int i = t; i < BDIM * SDIM; i += blockDim.x) {
        int v;
        if (okInt)        v = (int)raw[i];            // int32 storage, values 0/1
        else if (okFloat) v = (raw[i] != 0u) ? 1 : 0; // float32 storage 0.0/1.0
        else              v = (int)rb[i];             // 1-byte bool storage
        out[i] = v ? -1e30f : 0.0f;
    }
}

// ---------------------------------------------------------------------------
// C = (A @ W^T + bias) * scale.  A: MDIMxEDIM (fp32 or bf16), W: EDIMxEDIM fp32.
// mode=0: fp32 row-major MDIMxEDIM (final output)
// mode=1: bf16 scatter to [b*H+h][s][d]      (Q, K)
// mode=2: bf16 scatter to [b*H+h][d][s]      (V transposed for PV fragments)
// ---------------------------------------------------------------------------
__global__ __launch_bounds__(256) void gemm_xwT(
    const float* __restrict__ Af, const u16* __restrict__ Ab, int a_bf16,
    const float* __restrict__ W, const float* __restrict__ bias, float scale,
    u16* __restrict__ out_sc, float* __restrict__ out_rm, int mode)
{
    __shared__ u16 Al[64 * 56];
    __shared__ u16 Bl[64 * 56];
    int tid = threadIdx.x;
    int mb = blockIdx.x * 64, nb = blockIdx.y * 64;
    int lane = tid & 63, w = tid >> 6;
    int r16 = lane & 15, g4 = lane >> 4;
    int wm = w >> 1, wn = w & 1;

    f32x4 acc[2][2];
    acc[0][0] = zero4(); acc[0][1] = zero4(); acc[1][0] = zero4(); acc[1][1] = zero4();

    int srow = tid >> 2, scol = (tid & 3) * 8;

    for (int kb = 0; kb < EDIM; kb += 32) {
        __syncthreads();
        if (a_bf16) {
            *(uint4*)&Al[srow * 56 + scol] =
                *(const uint4*)&Ab[(size_t)(mb + srow) * EDIM + kb + scol];
        } else {
            const float* s = Af + (size_t)(mb + srow) * EDIM + kb + scol;
            float4 x0 = *(const float4*)s, x1 = *(const float4*)(s + 4);
            u16* d = &Al[srow * 56 + scol];
            d[0] = f2b(x0.x); d[1] = f2b(x0.y); d[2] = f2b(x0.z); d[3] = f2b(x0.w);
            d[4] = f2b(x1.x); d[5] = f2b(x1.y); d[6] = f2b(x1.z); d[7] = f2b(x1.w);
        }
        {
            const float* s = W + (size_t)(nb + srow) * EDIM + kb + scol;
            float4 x0 = *(const float4*)s, x1 = *(const float4*)(s + 4);
            u16* d = &Bl[srow * 56 + scol];
            d[0] = f2b(x0.x); d[1] = f2b(x0.y); d[2] = f2b(x0.z); d[3] = f2b(x0.w);
            d[4] = f2b(x1.x); d[5] = f2b(x1.y); d[6] = f2b(x1.z); d[7] = f2b(x1.w);
        }
        __syncthreads();
        s16x8 a[2], bb[2];
        #pragma unroll
        for (int mi = 0; mi < 2; ++mi)
            a[mi] = *(const s16x8*)&Al[(wm * 32 + mi * 16 + r16) * 56 + g4 * 8];
        #pragma unroll
        for (int ni = 0; ni < 2; ++ni)
            bb[ni] = *(const s16x8*)&Bl[(wn * 32 + ni * 16 + r16) * 56 + g4 * 8];
        #pragma unroll
        for (int mi = 0; mi < 2; ++mi)
            #pragma unroll
            for (int ni = 0; ni < 2; ++ni)
                acc[mi][ni] = mfma16(a[mi], bb[ni], acc[mi][ni]);
    }

    #pragma unroll
    for (int mi = 0; mi < 2; ++mi) {
        #pragma unroll
        for (int ni = 0; ni < 2; ++ni) {
            int n = nb + wn * 32 + ni * 16 + r16;
            float bv = bias[n];
            #pragma unroll
            for (int r = 0; r < 4; ++r) {
                int m = mb + wm * 32 + mi * 16 + g4 * 4 + r;
                float c = (acc[mi][ni][r] + bv) * scale;
                if (mode == 1) {
                    int s_ = m >> 1, b_ = m & 1, h_ = n >> 6, d_ = n & 63;
                    out_sc[((size_t)(b_ * HDIM + h_) * SDIM + s_) * DDIM + d_] = f2b(c);
                } else if (mode == 2) {
                    int s_ = m >> 1, b_ = m & 1, h_ = n >> 6, d_ = n & 63;
                    out_sc[((size_t)(b_ * HDIM + h_) * DDIM + d_) * SDIM + s_] = f2b(c);
                } else {
                    out_rm[(size_t)m * EDIM + n] = c;
                }
            }
        }
    }
}

// ---------------------------------------------------------------------------
// Fused flash attention, split-K: 2 waves/block, wave w covers keys
// [w*1024, w*1024+1024). 16 q rows per block. Online softmax per wave;
// m/l/acc combined once at the end via LDS. Bias (the only HBM stream)
// register-prefetched one 32-key tile ahead. V read from transposed layout
// Vt[bh][d][s] -> contiguous 16B fragment loads (L2-resident). P transpose
// via wave-private LDS (no barriers in the loop).
// ---------------------------------------------------------------------------
__global__ __launch_bounds__(128) void attn_fused(
    const u16* __restrict__ qw, const u16* __restrict__ kw,
    const u16* __restrict__ vt, const float* __restrict__ bias,
    const float* __restrict__ maskF, u16* __restrict__ attn_out)
{
    __shared__ float As[2][16][65];      // partial O per wave
    __shared__ float Ml[2][16], Ll[2][16];
    __shared__ u16 Pl[2][16][40];        // wave-private P transpose buffers

    int qt = blockIdx.x, bh = blockIdx.y;
    int tid = threadIdx.x;
    int w = tid >> 6, lane = tid & 63;
    int r16 = lane & 15, g4 = lane >> 4;
    int qbase = qt * 16;
    int b_ = bh / HDIM, h_ = bh % HDIM;
    const u16* Q   = qw + (size_t)bh * SDIM * DDIM;
    const u16* Kp  = kw + (size_t)bh * SDIM * DDIM;
    const u16* Vtp = vt + (size_t)bh * DDIM * SDIM;
    const float* Brow = bias + (size_t)bh * SDIM * SDIM;
    const float* mF = maskF + b_ * SDIM;

    s16x8 qf[2];
    qf[0] = *(const s16x8*)&Q[(size_t)(qbase + r16) * DDIM + g4 * 8];
    qf[1] = *(const s16x8*)&Q[(size_t)(qbase + r16) * DDIM + g4 * 8 + 32];

    f32x4 accO[4];
    float m_run[4], l_run[4];
    #pragma unroll
    for (int dt = 0; dt < 4; ++dt) accO[dt] = zero4();
    #pragma unroll
    for (int r = 0; r < 4; ++r) { m_run[r] = -1e30f; l_run[r] = 0.f; }

    const int k0 = w * KSPLIT;

    // prefetch bias(+mask poison) for first tile
    float bn[8];
    #pragma unroll
    for (int kt = 0; kt < 2; ++kt) {
        int kcol = k0 + kt * 16 + r16;
        float mv = mF[kcol];
        #pragma unroll
        for (int r = 0; r < 4; ++r)
            bn[kt * 4 + r] = Brow[(size_t)(qbase + g4 * 4 + r) * SDIM + kcol] + mv;
    }

    for (int it = 0; it < KSPLIT / 32; ++it) {
        int kb = k0 + it * 32;
        float bc[8];
        #pragma unroll
        for (int i = 0; i < 8; ++i) bc[i] = bn[i];
        // issue next-tile bias prefetch
        if (it + 1 < KSPLIT / 32) {
            int kb2 = kb + 32;
            #pragma unroll
            for (int kt = 0; kt < 2; ++kt) {
                int kcol = kb2 + kt * 16 + r16;
                float mv = mF[kcol];
                #pragma unroll
                for (int r = 0; r < 4; ++r)
                    bn[kt * 4 + r] = Brow[(size_t)(qbase + g4 * 4 + r) * SDIM + kcol] + mv;
            }
        }
        // V fragments for this tile (issue early; consumed after softmax)
        s16x8 vf[4];
        #pragma unroll
        for (int dt = 0; dt < 4; ++dt)
            vf[dt] = *(const s16x8*)&Vtp[(size_t)(dt * 16 + r16) * SDIM + kb + g4 * 8];
        // QK^T: two 16x16 score tiles
        f32x4 sc[2];
        #pragma unroll
        for (int kt = 0; kt < 2; ++kt) {
            f32x4 a = zero4();
            #pragma unroll
            for (int c = 0; c < 2; ++c) {
                s16x8 kf = *(const s16x8*)&Kp[(size_t)(kb + kt * 16 + r16) * DDIM + g4 * 8 + c * 32];
                a = mfma16(qf[c], kf, a);
            }
            sc[kt] = a;
        }
        // bias + mask
        #pragma unroll
        for (int kt = 0; kt < 2; ++kt)
            #pragma unroll
            for (int r = 0; r < 4; ++r)
                sc[kt][r] += bc[kt * 4 + r];
        // online softmax (row = q across the 16 lanes of a lane-group)
        float alpha[4];
        #pragma unroll
        for (int r = 0; r < 4; ++r) {
            float bm = fmaxf(sc[0][r], sc[1][r]);
            #pragma unroll
            for (int off = 1; off < 16; off <<= 1) bm = fmaxf(bm, __shfl_xor(bm, off));
            float mn = fmaxf(m_run[r], bm);
            alpha[r] = __expf(m_run[r] - mn);
            float p0 = __expf(sc[0][r] - mn);
            float p1 = __expf(sc[1][r] - mn);
            float ps = p0 + p1;
            #pragma unroll
            for (int off = 1; off < 16; off <<= 1) ps += __shfl_xor(ps, off);
            l_run[r] = l_run[r] * alpha[r] + ps;
            m_run[r] = mn;
            Pl[w][g4 * 4 + r][r16]      = f2b(p0);
            Pl[w][g4 * 4 + r][16 + r16] = f2b(p1);
        }
        #pragma unroll
        for (int dt = 0; dt < 4; ++dt) {
            accO[dt][0] *= alpha[0];
            accO[dt][1] *= alpha[1];
            accO[dt][2] *= alpha[2];
            accO[dt][3] *= alpha[3];
        }
        // PV (wave-private LDS transpose of P; in-order DS ops, no barrier)
        s16x8 pf = *(const s16x8*)&Pl[w][r16][g4 * 8];
        #pragma unroll
        for (int dt = 0; dt < 4; ++dt)
            accO[dt] = mfma16(pf, vf[dt], accO[dt]);
    }

    // --- combine the two waves' partials ---
    #pragma unroll
    for (int dt = 0; dt < 4; ++dt)
        #pragma unroll
        for (int r = 0; r < 4; ++r)
            As[w][g4 * 4 + r][dt * 16 + r16] = accO[dt][r];
    if (r16 == 0) {
        #pragma unroll
        for (int r = 0; r < 4; ++r) {
            Ml[w][g4 * 4 + r] = m_run[r];
            Ll[w][g4 * 4 + r] = l_run[r];
        }
    }
    __syncthreads();
    #pragma unroll
    for (int dtl = 0; dtl < 2; ++dtl) {
        int dt = w * 2 + dtl;
        #pragma unroll
        for (int r = 0; r < 4; ++r) {
            int q = g4 * 4 + r;
            float m0 = Ml[0][q], m1 = Ml[1][q];
            float mt = fmaxf(m0, m1);
            float e0 = __expf(m0 - mt), e1 = __expf(m1 - mt);
            float lt = Ll[0][q] * e0 + Ll[1][q] * e1;
            float o = (As[0][q][dt * 16 + r16] * e0 + As[1][q][dt * 16 + r16] * e1) / lt;
            attn_out[((size_t)(qbase + q) * BDIM + b_) * EDIM + h_ * DDIM + dt * 16 + r16] = f2b(o);
        }
    }
}

extern "C" void kernel_launch(void* const* d_in, const int* in_sizes, int n_in,
                              void* d_out, int out_size, void* d_ws, size_t ws_size,
                              hipStream_t stream) {
    const float* query     = (const float*)d_in[0];
    const float* attn_bias = (const float*)d_in[1];
    const u32*   mask_raw  = (const u32*)d_in[2];
    const float* Wq = (const float*)d_in[3];
    const float* bq = (const float*)d_in[4];
    const float* Wk = (const float*)d_in[5];
    const float* bk = (const float*)d_in[6];
    const float* Wv = (const float*)d_in[7];
    const float* bv = (const float*)d_in[8];
    const float* Wo = (const float*)d_in[9];
    const float* bo = (const float*)d_in[10];
    float* out = (float*)d_out;

    // workspace layout: maskF(16KB) | q | k | vt | attn   (bf16 head tensors)
    char* ws = (char*)d_ws;
    float* maskF = (float*)ws;
    const size_t HEADSZ = (size_t)BDIM * HDIM * SDIM * DDIM;  // 3,145,728 elems
    u16* qws = (u16*)(ws + 16384);
    u16* kws = qws + HEADSZ;
    u16* vws = kws + HEADSZ;
    u16* aws = vws + HEADSZ;

    mask_norm_kernel<<<1, 256, 0, stream>>>(mask_raw, maskF);

    dim3 gg(MDIM / 64, EDIM / 64);
    gemm_xwT<<<gg, 256, 0, stream>>>(query, nullptr, 0, Wq, bq, SCALE_Q, qws, nullptr, 1);
    gemm_xwT<<<gg, 256, 0, stream>>>(query, nullptr, 0, Wk, bk, 1.0f,    kws, nullptr, 1);
    gemm_xwT<<<gg, 256, 0, stream>>>(query, nullptr, 0, Wv, bv, 1.0f,    vws, nullptr, 2);

    dim3 ga(SDIM / 16, BDIM * HDIM);
    attn_fused<<<ga, 128, 0, stream>>>(qws, kws, vws, attn_bias, maskF, aws);

    gemm_xwT<<<gg, 256, 0, stream>>>(nullptr, aws, 1, Wo, bo, 1.0f, nullptr, out, 0);
}

// Round 3
// 341.641 us; speedup vs baseline: 1.1120x; 1.1120x over previous
//
#include <hip/hip_runtime.h>
#include <hip/hip_bf16.h>

typedef __attribute__((ext_vector_type(8))) short s16x8;   // 8 bf16 (4 VGPRs)
typedef __attribute__((ext_vector_type(4))) float f32x4;
typedef unsigned short u16;
typedef unsigned int u32;

#define SDIM 2048
#define BDIM 2
#define HDIM 12
#define DDIM 64
#define EDIM 768
#define MDIM 4096          // S*B rows
#define SCALE_Q 0.125f     // D^-0.5
#define KSPLIT 1024        // keys per wave (2 waves split the 2048-key range)
#define NIT (KSPLIT / 32)  // 32 iterations per wave

static __device__ __forceinline__ f32x4 zero4() {
    f32x4 v; v[0] = v[1] = v[2] = v[3] = 0.f; return v;
}

// fp32 -> bf16 bits, round-to-nearest-even
static __device__ __forceinline__ u16 f2b(float x) {
    u32 u = __builtin_bit_cast(u32, x);
    u32 lsb = (u >> 16) & 1u;
    u += 0x7fffu + lsb;
    return (u16)(u >> 16);
}

static __device__ __forceinline__ f32x4 mfma16(s16x8 a, s16x8 b, f32x4 c) {
    return __builtin_amdgcn_mfma_f32_16x16x32_bf16(a, b, c, 0, 0, 0);
}

// async global -> LDS, 16B per lane. LDS dest = wave-uniform base + lane*16.
static __device__ __forceinline__ void gload_lds16(const void* g, void* l) {
    __builtin_amdgcn_global_load_lds(
        (const __attribute__((address_space(1))) void*)g,
        (__attribute__((address_space(3))) void*)l, 16, 0, 0);
}

// ---------------------------------------------------------------------------
// key_padding_mask arrives with unknown storage (bool bytes / int32 / float32).
// Detect encoding (deterministic) and emit float poison: masked -> -1e30, else 0.
// ---------------------------------------------------------------------------
__global__ void mask_norm_kernel(const u32* __restrict__ raw, float* __restrict__ out) {
    __shared__ int okInt, okFloat;
    int t = threadIdx.x;
    if (t == 0) { okInt = 1; okFloat = 1; }
    __syncthreads();
    int li = 1, lf = 1;
    for (int i = t; i < 1024; i += blockDim.x) {
        u32 v = raw[i];
        if (v > 1u) li = 0;
        if (v != 0u && v != 0x3F800000u) lf = 0;
    }
    if (!li) atomicAnd(&okInt, 0);
    if (!lf) atomicAnd(&okFloat, 0);
    __syncthreads();
    const unsigned char* rb = (const unsigned char*)raw;
    for (int i = t; i < BDIM * SDIM; i += blockDim.x) {
        int v;
        if (okInt)        v = (int)raw[i];            // int32 storage, values 0/1
        else if (okFloat) v = (raw[i] != 0u) ? 1 : 0; // float32 storage 0.0/1.0
        else              v = (int)rb[i];             // 1-byte bool storage
        out[i] = v ? -1e30f : 0.0f;
    }
}

// ---------------------------------------------------------------------------
// C = (A @ W^T + bias) * scale.  A: MDIMxEDIM (fp32 or bf16), W: EDIMxEDIM fp32.
// mode=0: fp32 row-major MDIMxEDIM (final output)
// mode=1: bf16 scatter to [b*H+h][s][d]      (Q, K)
// mode=2: bf16 scatter to [b*H+h][d][s]      (V transposed for PV fragments)
// ---------------------------------------------------------------------------
__global__ __launch_bounds__(256) void gemm_xwT(
    const float* __restrict__ Af, const u16* __restrict__ Ab, int a_bf16,
    const float* __restrict__ W, const float* __restrict__ bias, float scale,
    u16* __restrict__ out_sc, float* __restrict__ out_rm, int mode)
{
    __shared__ u16 Al[64 * 56];
    __shared__ u16 Bl[64 * 56];
    int tid = threadIdx.x;
    int mb = blockIdx.x * 64, nb = blockIdx.y * 64;
    int lane = tid & 63, w = tid >> 6;
    int r16 = lane & 15, g4 = lane >> 4;
    int wm = w >> 1, wn = w & 1;

    f32x4 acc[2][2];
    acc[0][0] = zero4(); acc[0][1] = zero4(); acc[1][0] = zero4(); acc[1][1] = zero4();

    int srow = tid >> 2, scol = (tid & 3) * 8;

    for (int kb = 0; kb < EDIM; kb += 32) {
        __syncthreads();
        if (a_bf16) {
            *(uint4*)&Al[srow * 56 + scol] =
                *(const uint4*)&Ab[(size_t)(mb + srow) * EDIM + kb + scol];
        } else {
            const float* s = Af + (size_t)(mb + srow) * EDIM + kb + scol;
            float4 x0 = *(const float4*)s, x1 = *(const float4*)(s + 4);
            u16* d = &Al[srow * 56 + scol];
            d[0] = f2b(x0.x); d[1] = f2b(x0.y); d[2] = f2b(x0.z); d[3] = f2b(x0.w);
            d[4] = f2b(x1.x); d[5] = f2b(x1.y); d[6] = f2b(x1.z); d[7] = f2b(x1.w);
        }
        {
            const float* s = W + (size_t)(nb + srow) * EDIM + kb + scol;
            float4 x0 = *(const float4*)s, x1 = *(const float4*)(s + 4);
            u16* d = &Bl[srow * 56 + scol];
            d[0] = f2b(x0.x); d[1] = f2b(x0.y); d[2] = f2b(x0.z); d[3] = f2b(x0.w);
            d[4] = f2b(x1.x); d[5] = f2b(x1.y); d[6] = f2b(x1.z); d[7] = f2b(x1.w);
        }
        __syncthreads();
        s16x8 a[2], bb[2];
        #pragma unroll
        for (int mi = 0; mi < 2; ++mi)
            a[mi] = *(const s16x8*)&Al[(wm * 32 + mi * 16 + r16) * 56 + g4 * 8];
        #pragma unroll
        for (int ni = 0; ni < 2; ++ni)
            bb[ni] = *(const s16x8*)&Bl[(wn * 32 + ni * 16 + r16) * 56 + g4 * 8];
        #pragma unroll
        for (int mi = 0; mi < 2; ++mi)
            #pragma unroll
            for (int ni = 0; ni < 2; ++ni)
                acc[mi][ni] = mfma16(a[mi], bb[ni], acc[mi][ni]);
    }

    #pragma unroll
    for (int mi = 0; mi < 2; ++mi) {
        #pragma unroll
        for (int ni = 0; ni < 2; ++ni) {
            int n = nb + wn * 32 + ni * 16 + r16;
            float bv = bias[n];
            #pragma unroll
            for (int r = 0; r < 4; ++r) {
                int m = mb + wm * 32 + mi * 16 + g4 * 4 + r;
                float c = (acc[mi][ni][r] + bv) * scale;
                if (mode == 1) {
                    int s_ = m >> 1, b_ = m & 1, h_ = n >> 6, d_ = n & 63;
                    out_sc[((size_t)(b_ * HDIM + h_) * SDIM + s_) * DDIM + d_] = f2b(c);
                } else if (mode == 2) {
                    int s_ = m >> 1, b_ = m & 1, h_ = n >> 6, d_ = n & 63;
                    out_sc[((size_t)(b_ * HDIM + h_) * DDIM + d_) * SDIM + s_] = f2b(c);
                } else {
                    out_rm[(size_t)m * EDIM + n] = c;
                }
            }
        }
    }
}

// ---------------------------------------------------------------------------
// Fused flash attention v3.
// Grid (S/16, B*H); block = 128 threads = 2 waves; wave w handles keys
// [w*1024, w*1024+1024) for the block's 16 q-rows; combined at the end.
//
// Swapped QK^T: sc = mfma(K, Q) -> S[k][q], k lane-local (reg r + 16*kt tiles,
// k = 16*kt + 4*g4 + r; q = r16). Softmax reduce = in-lane tree + 2 shfl_xor.
//
// All tiles staged wave-privately via global_load_lds (coalesced 1KB/instr),
// with XOR-swizzled SOURCE addresses (linear LDS dest) so swizzled
// ds_read_b128 fragment reads are ~conflict-free. No barriers in the loop.
// Per-wave LDS (11520 B): Kl[32][8q] | Vl[64][4q] | Bs[16][8q] | Pl[16][40]
// ---------------------------------------------------------------------------
__global__ __launch_bounds__(128) void attn_fused(
    const u16* __restrict__ qw, const u16* __restrict__ kw,
    const u16* __restrict__ vt, const float* __restrict__ bias,
    const float* __restrict__ maskF, u16* __restrict__ attn_out)
{
    __shared__ unsigned char SM[23040];

    int qt = blockIdx.x, bh = blockIdx.y;
    int tid = threadIdx.x;
    int w = tid >> 6, lane = tid & 63;
    int r16 = lane & 15, g4 = lane >> 4;
    int qbase = qt * 16;
    int b_ = bh / HDIM, h_ = bh % HDIM;
    const u16* Q   = qw + (size_t)bh * SDIM * DDIM;
    const u16* Kp  = kw + (size_t)bh * SDIM * DDIM;
    const u16* Vtp = vt + (size_t)bh * DDIM * SDIM;
    const float* Brow = bias + (size_t)bh * SDIM * SDIM;
    const float* mF = maskF + b_ * SDIM;

    unsigned char* wbase = SM + w * 11520;
    u16*   Kl = (u16*)wbase;               // 32 rows x 8 quads (4096 B)
    u16*   Vl = (u16*)(wbase + 4096);      // 64 rows x 4 quads (4096 B)
    float* Bs = (float*)(wbase + 8192);    // 16 rows x 8 quads (2048 B)
    u16*   Pl = (u16*)(wbase + 10240);     // 16 x 40 (1280 B)

    // Q fragments (B-operand): rows q=r16, d-slice g4*8 + 32c
    s16x8 qf[2];
    qf[0] = *(const s16x8*)&Q[(size_t)(qbase + r16) * DDIM + g4 * 8];
    qf[1] = *(const s16x8*)&Q[(size_t)(qbase + r16) * DDIM + g4 * 8 + 32];

    f32x4 accO[4];
    #pragma unroll
    for (int dt = 0; dt < 4; ++dt) accO[dt] = zero4();
    float m_run = -1e30f, l_run = 0.f;   // for column q = r16 (x4 copies)

    const int k0 = w * KSPLIT;

    // ---- staging: 10 global_load_lds, XOR-swizzled source, linear dest ----
    auto stage = [&](int kb) {
        #pragma unroll
        for (int j = 0; j < 4; ++j) {              // K tile: 32 rows x 128 B
            int slot = j * 64 + lane;
            int krow = slot >> 3, q8 = slot & 7;
            int sq = q8 ^ (krow & 7);
            gload_lds16(&Kp[(size_t)(kb + krow) * DDIM + sq * 8], Kl + j * 512);
        }
        #pragma unroll
        for (int j = 0; j < 4; ++j) {              // V tile: 64 rows x 64 B
            int slot = j * 64 + lane;
            int drow = slot >> 2, kq = slot & 3;
            int sq = kq ^ ((slot >> 3) & 3);       // = kq ^ ((drow>>1)&3)
            gload_lds16(&Vtp[(size_t)drow * SDIM + kb + sq * 8], Vl + j * 512);
        }
        #pragma unroll
        for (int j = 0; j < 2; ++j) {              // bias tile: 16 rows x 128 B
            int slot = j * 64 + lane;
            int row = slot >> 3, q8 = slot & 7;
            int sq = q8 ^ (row & 7);
            gload_lds16(&Brow[(size_t)(qbase + row) * SDIM + kb + sq * 4], Bs + j * 256);
        }
    };

    stage(k0);

    for (int it = 0; it < NIT; ++it) {
        int kb = k0 + it * 32;
        // wait staged tiles
        asm volatile("s_waitcnt vmcnt(0)" ::: "memory");
        __builtin_amdgcn_sched_barrier(0);

        // fragment reads (swizzled)
        s16x8 kf[2][2];
        #pragma unroll
        for (int kt = 0; kt < 2; ++kt) {
            int krow = kt * 16 + r16;
            #pragma unroll
            for (int c = 0; c < 2; ++c) {
                int qd = (g4 + 4 * c) ^ (krow & 7);
                kf[kt][c] = *(const s16x8*)&Kl[krow * 64 + qd * 8];
            }
        }
        s16x8 vf[4];
        #pragma unroll
        for (int dt = 0; dt < 4; ++dt) {
            int drow = dt * 16 + r16;
            int kq = g4 ^ ((r16 >> 1) & 3);
            vf[dt] = *(const s16x8*)&Vl[drow * 32 + kq * 8];
        }
        float4 bc[2];
        #pragma unroll
        for (int kt = 0; kt < 2; ++kt) {
            int qd = (g4 + 4 * kt) ^ (r16 & 7);
            bc[kt] = *(const float4*)&Bs[r16 * 32 + qd * 4];
        }
        // mask poison (tiny, L1-hot): 4 floats = this lane's k positions
        float4 mv[2];
        #pragma unroll
        for (int kt = 0; kt < 2; ++kt)
            mv[kt] = *(const float4*)&mF[kb + kt * 16 + g4 * 4];

        // all LDS reads landed -> safe to overwrite tiles with next stage
        asm volatile("s_waitcnt lgkmcnt(0)" ::: "memory");
        __builtin_amdgcn_sched_barrier(0);
        if (it + 1 < NIT) stage(kb + 32);

        // QK^T swapped: sc[kt] = S[k = 16kt+4g4+r][q = r16]
        f32x4 sc[2];
        #pragma unroll
        for (int kt = 0; kt < 2; ++kt)
            sc[kt] = mfma16(kf[kt][1], qf[1], mfma16(kf[kt][0], qf[0], zero4()));
        #pragma unroll
        for (int kt = 0; kt < 2; ++kt) {
            sc[kt][0] += bc[kt].x + mv[kt].x;
            sc[kt][1] += bc[kt].y + mv[kt].y;
            sc[kt][2] += bc[kt].z + mv[kt].z;
            sc[kt][3] += bc[kt].w + mv[kt].w;
        }

        // online softmax for column q = r16 (32 keys: 8 in-lane x 4 groups)
        float pm = fmaxf(fmaxf(fmaxf(sc[0][0], sc[0][1]), fmaxf(sc[0][2], sc[0][3])),
                         fmaxf(fmaxf(sc[1][0], sc[1][1]), fmaxf(sc[1][2], sc[1][3])));
        pm = fmaxf(pm, __shfl_xor(pm, 16));
        pm = fmaxf(pm, __shfl_xor(pm, 32));
        float mn = fmaxf(m_run, pm);
        float alpha = __expf(m_run - mn);
        float p[8];
        #pragma unroll
        for (int kt = 0; kt < 2; ++kt)
            #pragma unroll
            for (int r = 0; r < 4; ++r)
                p[kt * 4 + r] = __expf(sc[kt][r] - mn);
        float ps = ((p[0] + p[1]) + (p[2] + p[3])) + ((p[4] + p[5]) + (p[6] + p[7]));
        ps += __shfl_xor(ps, 16);
        ps += __shfl_xor(ps, 32);
        l_run = l_run * alpha + ps;
        m_run = mn;

        // P -> bf16, packed writes: Pl[q = r16][k = 16kt+4g4 + 0..3]
        #pragma unroll
        for (int kt = 0; kt < 2; ++kt) {
            uint2 pv;
            pv.x = (u32)f2b(p[kt * 4 + 0]) | ((u32)f2b(p[kt * 4 + 1]) << 16);
            pv.y = (u32)f2b(p[kt * 4 + 2]) | ((u32)f2b(p[kt * 4 + 3]) << 16);
            *(uint2*)&Pl[r16 * 40 + kt * 16 + g4 * 4] = pv;
        }

        // redistribute alpha (column-form lane r16=q) to row-form q = g4*4+r
        float aR[4];
        #pragma unroll
        for (int r = 0; r < 4; ++r)
            aR[r] = __shfl(alpha, g4 * 4 + r);
        #pragma unroll
        for (int dt = 0; dt < 4; ++dt) {
            accO[dt][0] *= aR[0];
            accO[dt][1] *= aR[1];
            accO[dt][2] *= aR[2];
            accO[dt][3] *= aR[3];
        }

        // PV: A = P rows q=r16 (k-slice g4*8), B = V
        s16x8 pf = *(const s16x8*)&Pl[r16 * 40 + g4 * 8];
        #pragma unroll
        for (int dt = 0; dt < 4; ++dt)
            accO[dt] = mfma16(pf, vf[dt], accO[dt]);
    }

    // ---- combine the two waves' partials (reuse staging LDS) ----
    __syncthreads();
    float* As = (float*)SM;                 // [2][16][68]
    float* Ml = (float*)(SM + 8704);        // [2][16]
    float* Ll = Ml + 32;
    #pragma unroll
    for (int dt = 0; dt < 4; ++dt)
        #pragma unroll
        for (int r = 0; r < 4; ++r)
            As[(w * 16 + g4 * 4 + r) * 68 + dt * 16 + r16] = accO[dt][r];
    if (g4 == 0) { Ml[w * 16 + r16] = m_run; Ll[w * 16 + r16] = l_run; }
    __syncthreads();

    #pragma unroll
    for (int half = 0; half < 2; ++half) {
        int d = w * 32 + half * 16 + r16;
        #pragma unroll
        for (int r = 0; r < 4; ++r) {
            int q = g4 * 4 + r;
            float m0 = Ml[q], m1 = Ml[16 + q];
            float mt = fmaxf(m0, m1);
            float e0 = __expf(m0 - mt), e1 = __expf(m1 - mt);
            float lt = Ll[q] * e0 + Ll[16 + q] * e1;
            float o = (As[q * 68 + d] * e0 + As[(16 + q) * 68 + d] * e1) / lt;
            attn_out[((size_t)(qbase + q) * BDIM + b_) * EDIM + h_ * DDIM + d] = f2b(o);
        }
    }
}

extern "C" void kernel_launch(void* const* d_in, const int* in_sizes, int n_in,
                              void* d_out, int out_size, void* d_ws, size_t ws_size,
                              hipStream_t stream) {
    const float* query     = (const float*)d_in[0];
    const float* attn_bias = (const float*)d_in[1];
    const u32*   mask_raw  = (const u32*)d_in[2];
    const float* Wq = (const float*)d_in[3];
    const float* bq = (const float*)d_in[4];
    const float* Wk = (const float*)d_in[5];
    const float* bk = (const float*)d_in[6];
    const float* Wv = (const float*)d_in[7];
    const float* bv = (const float*)d_in[8];
    const float* Wo = (const float*)d_in[9];
    const float* bo = (const float*)d_in[10];
    float* out = (float*)d_out;

    // workspace layout: maskF(16KB) | q | k | vt | attn   (bf16 head tensors)
    char* ws = (char*)d_ws;
    float* maskF = (float*)ws;
    const size_t HEADSZ = (size_t)BDIM * HDIM * SDIM * DDIM;  // 3,145,728 elems
    u16* qws = (u16*)(ws + 16384);
    u16* kws = qws + HEADSZ;
    u16* vws = kws + HEADSZ;
    u16* aws = vws + HEADSZ;

    mask_norm_kernel<<<1, 256, 0, stream>>>(mask_raw, maskF);

    dim3 gg(MDIM / 64, EDIM / 64);
    gemm_xwT<<<gg, 256, 0, stream>>>(query, nullptr, 0, Wq, bq, SCALE_Q, qws, nullptr, 1);
    gemm_xwT<<<gg, 256, 0, stream>>>(query, nullptr, 0, Wk, bk, 1.0f,    kws, nullptr, 1);
    gemm_xwT<<<gg, 256, 0, stream>>>(query, nullptr, 0, Wv, bv, 1.0f,    vws, nullptr, 2);

    dim3 ga(SDIM / 16, BDIM * HDIM);
    attn_fused<<<ga, 128, 0, stream>>>(qws, kws, vws, attn_bias, maskF, aws);

    gemm_xwT<<<gg, 256, 0, stream>>>(nullptr, aws, 1, Wo, bo, 1.0f, nullptr, out, 0);
}

// Round 4
// 327.460 us; speedup vs baseline: 1.1602x; 1.0433x over previous
//
#include <hip/hip_runtime.h>
#include <hip/hip_bf16.h>

typedef __attribute__((ext_vector_type(8))) short s16x8;   // 8 bf16 (4 VGPRs)
typedef __attribute__((ext_vector_type(4))) float f32x4;
typedef unsigned short u16;
typedef unsigned int u32;

#define SDIM 2048
#define BDIM 2
#define HDIM 12
#define DDIM 64
#define EDIM 768
#define MDIM 4096          // S*B rows
#define SCALE_Q 0.125f     // D^-0.5
#define KSPLIT 1024        // keys per wave (2 waves split the 2048-key range)
#define NIT (KSPLIT / 32)  // 32 iterations per wave
#define HFRAG 131072       // per-head fragment-tensor elements (2048*64)

static __device__ __forceinline__ f32x4 zero4() {
    f32x4 v; v[0] = v[1] = v[2] = v[3] = 0.f; return v;
}

// fp32 -> bf16 bits, round-to-nearest-even
static __device__ __forceinline__ u16 f2b(float x) {
    u32 u = __builtin_bit_cast(u32, x);
    u32 lsb = (u >> 16) & 1u;
    u += 0x7fffu + lsb;
    return (u16)(u >> 16);
}

static __device__ __forceinline__ f32x4 mfma16(s16x8 a, s16x8 b, f32x4 c) {
    return __builtin_amdgcn_mfma_f32_16x16x32_bf16(a, b, c, 0, 0, 0);
}

// ---------------------------------------------------------------------------
// key_padding_mask arrives with unknown storage (bool bytes / int32 / float32).
// Detect encoding (deterministic) and emit float poison: masked -> -1e30, else 0.
// ---------------------------------------------------------------------------
__global__ void mask_norm_kernel(const u32* __restrict__ raw, float* __restrict__ out) {
    __shared__ int okInt, okFloat;
    int t = threadIdx.x;
    if (t == 0) { okInt = 1; okFloat = 1; }
    __syncthreads();
    int li = 1, lf = 1;
    for (int i = t; i < 1024; i += blockDim.x) {
        u32 v = raw[i];
        if (v > 1u) li = 0;
        if (v != 0u && v != 0x3F800000u) lf = 0;
    }
    if (!li) atomicAnd(&okInt, 0);
    if (!lf) atomicAnd(&okFloat, 0);
    __syncthreads();
    const unsigned char* rb = (const unsigned char*)raw;
    for (int i = t; i < BDIM * SDIM; i += blockDim.x) {
        int v;
        if (okInt)        v = (int)raw[i];            // int32 storage, values 0/1
        else if (okFloat) v = (raw[i] != 0u) ? 1 : 0; // float32 storage 0.0/1.0
        else              v = (int)rb[i];             // 1-byte bool storage
        out[i] = v ? -1e30f : 0.0f;
    }
}

// ---------------------------------------------------------------------------
// C = (A @ W^T + bias) * scale.  A: MDIMxEDIM (fp32 or bf16), W: EDIMxEDIM fp32.
// mode=0: fp32 row-major MDIMxEDIM (final output)
// mode=1: bf16 scatter to [b*H+h][s][d]              (Q)
// mode=3: bf16 scatter to K fragment-major layout     (K)
//         p = bh*HFRAG + (s>>4)*1024 + ((d>>5)&1)*512 + (((d>>3)&3)*16+(s&15))*8 + (d&7)
// mode=4: bf16 scatter to V fragment-major layout     (V)
//         p = bh*HFRAG + (s>>5)*2048 + ((d>>4)&3)*512 + (((s>>3)&3)*16+(d&15))*8 + (s&7)
// ---------------------------------------------------------------------------
__global__ __launch_bounds__(256) void gemm_xwT(
    const float* __restrict__ Af, const u16* __restrict__ Ab, int a_bf16,
    const float* __restrict__ W, const float* __restrict__ bias, float scale,
    u16* __restrict__ out_sc, float* __restrict__ out_rm, int mode)
{
    __shared__ u16 Al[64 * 56];
    __shared__ u16 Bl[64 * 56];
    int tid = threadIdx.x;
    int mb = blockIdx.x * 64, nb = blockIdx.y * 64;
    int lane = tid & 63, w = tid >> 6;
    int r16 = lane & 15, g4 = lane >> 4;
    int wm = w >> 1, wn = w & 1;

    f32x4 acc[2][2];
    acc[0][0] = zero4(); acc[0][1] = zero4(); acc[1][0] = zero4(); acc[1][1] = zero4();

    int srow = tid >> 2, scol = (tid & 3) * 8;

    for (int kb = 0; kb < EDIM; kb += 32) {
        __syncthreads();
        if (a_bf16) {
            *(uint4*)&Al[srow * 56 + scol] =
                *(const uint4*)&Ab[(size_t)(mb + srow) * EDIM + kb + scol];
        } else {
            const float* s = Af + (size_t)(mb + srow) * EDIM + kb + scol;
            float4 x0 = *(const float4*)s, x1 = *(const float4*)(s + 4);
            u16* d = &Al[srow * 56 + scol];
            d[0] = f2b(x0.x); d[1] = f2b(x0.y); d[2] = f2b(x0.z); d[3] = f2b(x0.w);
            d[4] = f2b(x1.x); d[5] = f2b(x1.y); d[6] = f2b(x1.z); d[7] = f2b(x1.w);
        }
        {
            const float* s = W + (size_t)(nb + srow) * EDIM + kb + scol;
            float4 x0 = *(const float4*)s, x1 = *(const float4*)(s + 4);
            u16* d = &Bl[srow * 56 + scol];
            d[0] = f2b(x0.x); d[1] = f2b(x0.y); d[2] = f2b(x0.z); d[3] = f2b(x0.w);
            d[4] = f2b(x1.x); d[5] = f2b(x1.y); d[6] = f2b(x1.z); d[7] = f2b(x1.w);
        }
        __syncthreads();
        s16x8 a[2], bb[2];
        #pragma unroll
        for (int mi = 0; mi < 2; ++mi)
            a[mi] = *(const s16x8*)&Al[(wm * 32 + mi * 16 + r16) * 56 + g4 * 8];
        #pragma unroll
        for (int ni = 0; ni < 2; ++ni)
            bb[ni] = *(const s16x8*)&Bl[(wn * 32 + ni * 16 + r16) * 56 + g4 * 8];
        #pragma unroll
        for (int mi = 0; mi < 2; ++mi)
            #pragma unroll
            for (int ni = 0; ni < 2; ++ni)
                acc[mi][ni] = mfma16(a[mi], bb[ni], acc[mi][ni]);
    }

    #pragma unroll
    for (int mi = 0; mi < 2; ++mi) {
        #pragma unroll
        for (int ni = 0; ni < 2; ++ni) {
            int n = nb + wn * 32 + ni * 16 + r16;
            float bv = bias[n];
            #pragma unroll
            for (int r = 0; r < 4; ++r) {
                int m = mb + wm * 32 + mi * 16 + g4 * 4 + r;
                float c = (acc[mi][ni][r] + bv) * scale;
                if (mode == 1) {
                    int s_ = m >> 1, b_ = m & 1, h_ = n >> 6, d_ = n & 63;
                    out_sc[((size_t)(b_ * HDIM + h_) * SDIM + s_) * DDIM + d_] = f2b(c);
                } else if (mode == 3) {
                    int s_ = m >> 1, b_ = m & 1, h_ = n >> 6, d_ = n & 63;
                    size_t p = (size_t)(b_ * HDIM + h_) * HFRAG
                             + (size_t)(s_ >> 4) * 1024 + (size_t)((d_ >> 5) & 1) * 512
                             + (size_t)(((d_ >> 3) & 3) * 16 + (s_ & 15)) * 8 + (d_ & 7);
                    out_sc[p] = f2b(c);
                } else if (mode == 4) {
                    int s_ = m >> 1, b_ = m & 1, h_ = n >> 6, d_ = n & 63;
                    size_t p = (size_t)(b_ * HDIM + h_) * HFRAG
                             + (size_t)(s_ >> 5) * 2048 + (size_t)((d_ >> 4) & 3) * 512
                             + (size_t)(((s_ >> 3) & 3) * 16 + (d_ & 15)) * 8 + (s_ & 7);
                    out_sc[p] = f2b(c);
                } else {
                    out_rm[(size_t)m * EDIM + n] = c;
                }
            }
        }
    }
}

// ---------------------------------------------------------------------------
// Fused flash attention v4 — register-direct streams, no LDS staging.
// Grid (S/16, B*H); block = 128 threads = 2 waves; wave w covers keys
// [w*1024, w*1024+1024) for the block's 16 q-rows; combined at the end.
//
// Swapped QK^T (verified R3): sc = mfma(K,Q) -> S[k][q], k = 16kt+4g4+r, q = r16.
// K/V fragments: contiguous per-lane 16B loads from fragment-major tensors.
// Bias: per-lane float4 pairs, depth-2 register prefetch (unrolled x2 bodies).
// Only LDS in the loop: wave-private 1.28 KB P-transpose buffer (no barriers).
// ---------------------------------------------------------------------------
__global__ __launch_bounds__(128) void attn_fused(
    const u16* __restrict__ qw, const u16* __restrict__ kf_g,
    const u16* __restrict__ vf_g, const float* __restrict__ bias,
    const float* __restrict__ maskF, u16* __restrict__ attn_out)
{
    __shared__ unsigned char SM[9216];   // loop: 2x1280 P buffers; epilogue: combine

    int qt = blockIdx.x, bh = blockIdx.y;
    int tid = threadIdx.x;
    int w = tid >> 6, lane = tid & 63;
    int r16 = lane & 15, g4 = lane >> 4;
    int qbase = qt * 16;
    int b_ = bh / HDIM, h_ = bh % HDIM;
    const u16* Q  = qw   + (size_t)bh * SDIM * DDIM;
    const u16* KF = kf_g + (size_t)bh * HFRAG;
    const u16* VF = vf_g + (size_t)bh * HFRAG;
    const float* BrowQ = bias + (size_t)bh * SDIM * SDIM + (size_t)qbase * SDIM;
    const float* mF = maskF + b_ * SDIM;

    u16* Pl = (u16*)(SM + w * 1280);     // [16 q][40 k-padded]

    // Q fragments (B-operand): rows q = r16, d-slice g4*8 + 32c
    s16x8 qf[2];
    qf[0] = *(const s16x8*)&Q[(size_t)(qbase + r16) * DDIM + g4 * 8];
    qf[1] = *(const s16x8*)&Q[(size_t)(qbase + r16) * DDIM + g4 * 8 + 32];

    f32x4 accO[4];
    #pragma unroll
    for (int dt = 0; dt < 4; ++dt) accO[dt] = zero4();
    float m_run = -1e30f, l_run = 0.f;   // for column q = r16

    const int k0 = w * KSPLIT;
    const float* bp0 = BrowQ + (size_t)r16 * SDIM;

    // one 32-key iteration; c0/c1 are this tile's bias regs (refreshed for t+2)
    auto body = [&](int it, float4& c0, float4& c1) {
        int kb = k0 + it * 32;
        // K fragments: 2 16-key tiles x 2 d-halves, contiguous lane loads
        const u16* KT = KF + (size_t)(kb >> 4) * 1024;
        s16x8 kf0 = *(const s16x8*)&KT[lane * 8];
        s16x8 kf1 = *(const s16x8*)&KT[512 + lane * 8];
        s16x8 kf2 = *(const s16x8*)&KT[1024 + lane * 8];
        s16x8 kf3 = *(const s16x8*)&KT[1536 + lane * 8];
        // V fragments: 4 d-tiles, contiguous lane loads
        const u16* VT = VF + (size_t)(kb >> 5) * 2048;
        s16x8 vf[4];
        #pragma unroll
        for (int dt = 0; dt < 4; ++dt)
            vf[dt] = *(const s16x8*)&VT[dt * 512 + lane * 8];
        // mask poison (L1/L2-hot)
        float4 mv0 = *(const float4*)&mF[kb + g4 * 4];
        float4 mv1 = *(const float4*)&mF[kb + 16 + g4 * 4];

        // QK^T swapped: sc[kt] = S[k = 16kt+4g4+r][q = r16]
        f32x4 sc0 = mfma16(kf1, qf[1], mfma16(kf0, qf[0], zero4()));
        f32x4 sc1 = mfma16(kf3, qf[1], mfma16(kf2, qf[0], zero4()));
        sc0[0] += c0.x + mv0.x; sc0[1] += c0.y + mv0.y;
        sc0[2] += c0.z + mv0.z; sc0[3] += c0.w + mv0.w;
        sc1[0] += c1.x + mv1.x; sc1[1] += c1.y + mv1.y;
        sc1[2] += c1.z + mv1.z; sc1[3] += c1.w + mv1.w;

        // refresh bias regs for tile it+2 (depth-2 pipeline)
        if (it + 2 < NIT) {
            const float* bp = bp0 + (kb + 64);
            c0 = *(const float4*)(bp + g4 * 4);
            c1 = *(const float4*)(bp + 16 + g4 * 4);
        }

        // online softmax for column q = r16 (32 keys: 8 in-lane x 4 lane-groups)
        float pm = fmaxf(fmaxf(fmaxf(sc0[0], sc0[1]), fmaxf(sc0[2], sc0[3])),
                         fmaxf(fmaxf(sc1[0], sc1[1]), fmaxf(sc1[2], sc1[3])));
        pm = fmaxf(pm, __shfl_xor(pm, 16));
        pm = fmaxf(pm, __shfl_xor(pm, 32));
        float mn = fmaxf(m_run, pm);
        float alpha = __expf(m_run - mn);
        float p[8];
        #pragma unroll
        for (int r = 0; r < 4; ++r) p[r]     = __expf(sc0[r] - mn);
        #pragma unroll
        for (int r = 0; r < 4; ++r) p[4 + r] = __expf(sc1[r] - mn);
        float ps = ((p[0] + p[1]) + (p[2] + p[3])) + ((p[4] + p[5]) + (p[6] + p[7]));
        ps += __shfl_xor(ps, 16);
        ps += __shfl_xor(ps, 32);
        l_run = l_run * alpha + ps;
        m_run = mn;

        // P -> bf16, packed LDS writes: Pl[q = r16][k = 16kt + 4g4 + 0..3]
        uint2 pv0, pv1;
        pv0.x = (u32)f2b(p[0]) | ((u32)f2b(p[1]) << 16);
        pv0.y = (u32)f2b(p[2]) | ((u32)f2b(p[3]) << 16);
        pv1.x = (u32)f2b(p[4]) | ((u32)f2b(p[5]) << 16);
        pv1.y = (u32)f2b(p[6]) | ((u32)f2b(p[7]) << 16);
        *(uint2*)&Pl[r16 * 40 + g4 * 4]      = pv0;
        *(uint2*)&Pl[r16 * 40 + 16 + g4 * 4] = pv1;

        // alpha (held at lane r16=q) -> row-form q = 4g4+r for the rescale
        float aR[4];
        #pragma unroll
        for (int r = 0; r < 4; ++r) aR[r] = __shfl(alpha, g4 * 4 + r);
        #pragma unroll
        for (int dt = 0; dt < 4; ++dt) {
            accO[dt][0] *= aR[0];
            accO[dt][1] *= aR[1];
            accO[dt][2] *= aR[2];
            accO[dt][3] *= aR[3];
        }

        // PV: A = P rows q=r16 (k-slice g4*8), B = V fragments
        s16x8 pf = *(const s16x8*)&Pl[r16 * 40 + g4 * 8];
        #pragma unroll
        for (int dt = 0; dt < 4; ++dt)
            accO[dt] = mfma16(pf, vf[dt], accO[dt]);
    };

    // prologue: bias tiles 0 and 1 into the two named register sets
    float4 a0, a1, b0, b1;
    {
        const float* bp = bp0 + k0;
        a0 = *(const float4*)(bp + g4 * 4);
        a1 = *(const float4*)(bp + 16 + g4 * 4);
        b0 = *(const float4*)(bp + 32 + g4 * 4);
        b1 = *(const float4*)(bp + 48 + g4 * 4);
    }
    for (int i2 = 0; i2 < NIT; i2 += 2) {
        body(i2,     a0, a1);
        body(i2 + 1, b0, b1);
    }

    // ---- combine the two waves' partials (reuse LDS) ----
    __syncthreads();
    float* As = (float*)SM;                 // [2][16][68]
    float* Ml = (float*)(SM + 8704);        // [2][16]
    float* Ll = Ml + 32;
    #pragma unroll
    for (int dt = 0; dt < 4; ++dt)
        #pragma unroll
        for (int r = 0; r < 4; ++r)
            As[(w * 16 + g4 * 4 + r) * 68 + dt * 16 + r16] = accO[dt][r];
    if (g4 == 0) { Ml[w * 16 + r16] = m_run; Ll[w * 16 + r16] = l_run; }
    __syncthreads();

    #pragma unroll
    for (int half = 0; half < 2; ++half) {
        int d = w * 32 + half * 16 + r16;
        #pragma unroll
        for (int r = 0; r < 4; ++r) {
            int q = g4 * 4 + r;
            float m0 = Ml[q], m1 = Ml[16 + q];
            float mt = fmaxf(m0, m1);
            float e0 = __expf(m0 - mt), e1 = __expf(m1 - mt);
            float lt = Ll[q] * e0 + Ll[16 + q] * e1;
            float o = (As[q * 68 + d] * e0 + As[(16 + q) * 68 + d] * e1) / lt;
            attn_out[((size_t)(qbase + q) * BDIM + b_) * EDIM + h_ * DDIM + d] = f2b(o);
        }
    }
}

extern "C" void kernel_launch(void* const* d_in, const int* in_sizes, int n_in,
                              void* d_out, int out_size, void* d_ws, size_t ws_size,
                              hipStream_t stream) {
    const float* query     = (const float*)d_in[0];
    const float* attn_bias = (const float*)d_in[1];
    const u32*   mask_raw  = (const u32*)d_in[2];
    const float* Wq = (const float*)d_in[3];
    const float* bq = (const float*)d_in[4];
    const float* Wk = (const float*)d_in[5];
    const float* bk = (const float*)d_in[6];
    const float* Wv = (const float*)d_in[7];
    const float* bv = (const float*)d_in[8];
    const float* Wo = (const float*)d_in[9];
    const float* bo = (const float*)d_in[10];
    float* out = (float*)d_out;

    // workspace layout: maskF(16KB) | q | kfrag | vfrag | attn  (bf16 tensors)
    char* ws = (char*)d_ws;
    float* maskF = (float*)ws;
    const size_t HEADSZ = (size_t)BDIM * HDIM * SDIM * DDIM;  // 3,145,728 elems
    u16* qws = (u16*)(ws + 16384);
    u16* kws = qws + HEADSZ;
    u16* vws = kws + HEADSZ;
    u16* aws = vws + HEADSZ;

    mask_norm_kernel<<<1, 256, 0, stream>>>(mask_raw, maskF);

    dim3 gg(MDIM / 64, EDIM / 64);
    gemm_xwT<<<gg, 256, 0, stream>>>(query, nullptr, 0, Wq, bq, SCALE_Q, qws, nullptr, 1);
    gemm_xwT<<<gg, 256, 0, stream>>>(query, nullptr, 0, Wk, bk, 1.0f,    kws, nullptr, 3);
    gemm_xwT<<<gg, 256, 0, stream>>>(query, nullptr, 0, Wv, bv, 1.0f,    vws, nullptr, 4);

    dim3 ga(SDIM / 16, BDIM * HDIM);
    attn_fused<<<ga, 128, 0, stream>>>(qws, kws, vws, attn_bias, maskF, aws);

    gemm_xwT<<<gg, 256, 0, stream>>>(nullptr, aws, 1, Wo, bo, 1.0f, nullptr, out, 0);
}

// Round 5
// 257.791 us; speedup vs baseline: 1.4737x; 1.2703x over previous
//
#include <hip/hip_runtime.h>
#include <hip/hip_bf16.h>

typedef __attribute__((ext_vector_type(8))) short s16x8;   // 8 bf16 (4 VGPRs)
typedef __attribute__((ext_vector_type(4))) float f32x4;
typedef unsigned short u16;
typedef unsigned int u32;

#define SDIM 2048
#define BDIM 2
#define HDIM 12
#define DDIM 64
#define EDIM 768
#define MDIM 4096          // S*B rows
#define SCALE_Q 0.125f     // D^-0.5
#define KSPLIT 1024        // keys per wave (2 waves split the 2048-key range)
#define NIT (KSPLIT / 32)  // 32 iterations per wave
#define HFRAG 131072       // per-head fragment-tensor elements (2048*64)

static __device__ __forceinline__ f32x4 zero4() {
    f32x4 v; v[0] = v[1] = v[2] = v[3] = 0.f; return v;
}

// fp32 -> bf16 bits, round-to-nearest-even
static __device__ __forceinline__ u16 f2b(float x) {
    u32 u = __builtin_bit_cast(u32, x);
    u32 lsb = (u >> 16) & 1u;
    u += 0x7fffu + lsb;
    return (u16)(u >> 16);
}

static __device__ __forceinline__ f32x4 mfma16(s16x8 a, s16x8 b, f32x4 c) {
    return __builtin_amdgcn_mfma_f32_16x16x32_bf16(a, b, c, 0, 0, 0);
}

// async global -> LDS, 16B per lane. LDS dest = wave-uniform base + lane*16.
static __device__ __forceinline__ void gload_lds16(const void* g, void* l) {
    __builtin_amdgcn_global_load_lds(
        (const __attribute__((address_space(1))) void*)g,
        (__attribute__((address_space(3))) void*)l, 16, 0, 0);
}

// ---------------------------------------------------------------------------
// mask -> bitmask. Storage of the bool array is unknown (bool bytes / int32 /
// float32); detect encoding from bit patterns (deterministic), emit 128 u32s
// (bit k = key k masked).
// ---------------------------------------------------------------------------
__global__ void mask_bits_kernel(const u32* __restrict__ raw, u32* __restrict__ outbits) {
    __shared__ int okInt, okFloat;
    int t = threadIdx.x;
    if (t == 0) { okInt = 1; okFloat = 1; }
    __syncthreads();
    int li = 1, lf = 1;
    for (int i = t; i < 1024; i += blockDim.x) {
        u32 v = raw[i];
        if (v > 1u) li = 0;
        if (v != 0u && v != 0x3F800000u) lf = 0;
    }
    if (!li) atomicAnd(&okInt, 0);
    if (!lf) atomicAnd(&okFloat, 0);
    __syncthreads();
    const unsigned char* rb = (const unsigned char*)raw;
    if (t < (BDIM * SDIM) / 32) {
        u32 bits = 0;
        for (int j = 0; j < 32; ++j) {
            int i = t * 32 + j;
            int v;
            if (okInt)        v = (int)raw[i];
            else if (okFloat) v = (raw[i] != 0u) ? 1 : 0;
            else              v = (int)rb[i];
            bits |= (v ? 1u : 0u) << j;
        }
        outbits[t] = bits;
    }
}

// ---------------------------------------------------------------------------
// fp32 -> bf16 bulk conversion (8 elems/thread)
// ---------------------------------------------------------------------------
__global__ __launch_bounds__(256) void conv_f32_bf16(
    const float* __restrict__ s, u16* __restrict__ d, int n8)
{
    int i = blockIdx.x * 256 + threadIdx.x;
    if (i >= n8) return;
    float4 x0 = ((const float4*)s)[(size_t)i * 2];
    float4 x1 = ((const float4*)s)[(size_t)i * 2 + 1];
    uint4 o;
    o.x = (u32)f2b(x0.x) | ((u32)f2b(x0.y) << 16);
    o.y = (u32)f2b(x0.z) | ((u32)f2b(x0.w) << 16);
    o.z = (u32)f2b(x1.x) | ((u32)f2b(x1.y) << 16);
    o.w = (u32)f2b(x1.z) | ((u32)f2b(x1.w) << 16);
    ((uint4*)d)[i] = o;
}

// ---------------------------------------------------------------------------
// C = (A @ W^T + bias) * scale.  A: MDIMxEDIM bf16, W: EDIMxEDIM bf16.
// mode=0: fp32 row-major MDIMxEDIM (final output)
// mode=1: bf16 scatter to [b*H+h][s][d]              (Q)
// mode=3: bf16 scatter to K fragment-major layout     (K)
// mode=4: bf16 scatter to V fragment-major layout     (V)
// ---------------------------------------------------------------------------
__global__ __launch_bounds__(256) void gemm_xwT(
    const u16* __restrict__ A, const u16* __restrict__ Wb,
    const float* __restrict__ bias, float scale,
    u16* __restrict__ out_sc, float* __restrict__ out_rm, int mode)
{
    __shared__ u16 Al[64 * 56];
    __shared__ u16 Bl[64 * 56];
    int tid = threadIdx.x;
    int mb = blockIdx.x * 64, nb = blockIdx.y * 64;
    int lane = tid & 63, w = tid >> 6;
    int r16 = lane & 15, g4 = lane >> 4;
    int wm = w >> 1, wn = w & 1;

    f32x4 acc[2][2];
    acc[0][0] = zero4(); acc[0][1] = zero4(); acc[1][0] = zero4(); acc[1][1] = zero4();

    int srow = tid >> 2, scol = (tid & 3) * 8;

    for (int kb = 0; kb < EDIM; kb += 32) {
        __syncthreads();
        *(uint4*)&Al[srow * 56 + scol] =
            *(const uint4*)&A[(size_t)(mb + srow) * EDIM + kb + scol];
        *(uint4*)&Bl[srow * 56 + scol] =
            *(const uint4*)&Wb[(size_t)(nb + srow) * EDIM + kb + scol];
        __syncthreads();
        s16x8 a[2], bb[2];
        #pragma unroll
        for (int mi = 0; mi < 2; ++mi)
            a[mi] = *(const s16x8*)&Al[(wm * 32 + mi * 16 + r16) * 56 + g4 * 8];
        #pragma unroll
        for (int ni = 0; ni < 2; ++ni)
            bb[ni] = *(const s16x8*)&Bl[(wn * 32 + ni * 16 + r16) * 56 + g4 * 8];
        #pragma unroll
        for (int mi = 0; mi < 2; ++mi)
            #pragma unroll
            for (int ni = 0; ni < 2; ++ni)
                acc[mi][ni] = mfma16(a[mi], bb[ni], acc[mi][ni]);
    }

    #pragma unroll
    for (int mi = 0; mi < 2; ++mi) {
        #pragma unroll
        for (int ni = 0; ni < 2; ++ni) {
            int n = nb + wn * 32 + ni * 16 + r16;
            float bv = bias[n];
            #pragma unroll
            for (int r = 0; r < 4; ++r) {
                int m = mb + wm * 32 + mi * 16 + g4 * 4 + r;
                float c = (acc[mi][ni][r] + bv) * scale;
                if (mode == 1) {
                    int s_ = m >> 1, b_ = m & 1, h_ = n >> 6, d_ = n & 63;
                    out_sc[((size_t)(b_ * HDIM + h_) * SDIM + s_) * DDIM + d_] = f2b(c);
                } else if (mode == 3) {
                    int s_ = m >> 1, b_ = m & 1, h_ = n >> 6, d_ = n & 63;
                    size_t p = (size_t)(b_ * HDIM + h_) * HFRAG
                             + (size_t)(s_ >> 4) * 1024 + (size_t)((d_ >> 5) & 1) * 512
                             + (size_t)(((d_ >> 3) & 3) * 16 + (s_ & 15)) * 8 + (d_ & 7);
                    out_sc[p] = f2b(c);
                } else if (mode == 4) {
                    int s_ = m >> 1, b_ = m & 1, h_ = n >> 6, d_ = n & 63;
                    size_t p = (size_t)(b_ * HDIM + h_) * HFRAG
                             + (size_t)(s_ >> 5) * 2048 + (size_t)((d_ >> 4) & 3) * 512
                             + (size_t)(((s_ >> 3) & 3) * 16 + (d_ & 15)) * 8 + (s_ & 7);
                    out_sc[p] = f2b(c);
                } else {
                    out_rm[(size_t)m * EDIM + n] = c;
                }
            }
        }
    }
}

// ---------------------------------------------------------------------------
// Fused flash attention v5 — async bias staging with counted vmcnt (T3/T4).
// Grid (S/16, B*H); block = 128 = 2 waves; wave w covers keys [w*1024, +1024).
//
// Per iter t: [issue kv(t+1) regs (8 loads)] [stage bias(t+2) via
// global_load_lds (2 DMA)] [s_waitcnt vmcnt(12)] [compute tile t].
// vmcnt(12) = kv(t+1) 8 + stage(t+1..t+2) 4 -> forces kv(t) & bias(t) only;
// bias gets 2 full bodies of latency cover, never drains to 0.
// Tail: clamped dummy loads keep the outstanding count uniform.
// Mask: scalar u32 bitmask per 32-key tile (SGPR, no vmem).
// ---------------------------------------------------------------------------
struct KV { s16x8 k0, k1, k2, k3, v0, v1, v2, v3; };

__global__ __launch_bounds__(128, 4) void attn_fused(
    const u16* __restrict__ qw, const u16* __restrict__ kf_g,
    const u16* __restrict__ vf_g, const float* __restrict__ bias,
    const u32* __restrict__ maskBits, u16* __restrict__ attn_out)
{
    __shared__ __align__(1024) unsigned char SM[18944];
    // [0,16384): bias ring, 2 waves x 4 slots x 2048B. [16384,18944): P bufs.

    int qt = blockIdx.x, bh = blockIdx.y;
    int tid = threadIdx.x;
    int w = tid >> 6, lane = tid & 63;
    int r16 = lane & 15, g4 = lane >> 4;
    int qbase = qt * 16;
    int b_ = bh / HDIM, h_ = bh % HDIM;
    const u16* Q  = qw   + (size_t)bh * SDIM * DDIM;
    const u16* KF = kf_g + (size_t)bh * HFRAG;
    const u16* VF = vf_g + (size_t)bh * HFRAG;
    const float* BrowQ = bias + (size_t)bh * SDIM * SDIM + (size_t)qbase * SDIM;
    const u32* mB = maskBits + b_ * (SDIM / 32);

    float* BsW = (float*)(SM + w * 8192);          // 4 slots x 512 floats
    u16*   Pl  = (u16*)(SM + 16384 + w * 1280);    // [16 q][40 k-padded]

    s16x8 qf0 = *(const s16x8*)&Q[(size_t)(qbase + r16) * DDIM + g4 * 8];
    s16x8 qf1 = *(const s16x8*)&Q[(size_t)(qbase + r16) * DDIM + g4 * 8 + 32];

    f32x4 accO[4];
    #pragma unroll
    for (int dt = 0; dt < 4; ++dt) accO[dt] = zero4();
    float m_run = -1e30f, l_run = 0.f;   // for column q = r16

    const int k0 = w * KSPLIT;

    auto issue_kv = [&](int it, KV& dst) {
        int itc = it < NIT ? it : NIT - 1;           // clamped (uniform count)
        int kbn = k0 + itc * 32;
        const u16* KT = KF + (size_t)(kbn >> 4) * 1024;
        dst.k0 = *(const s16x8*)&KT[lane * 8];
        dst.k1 = *(const s16x8*)&KT[512 + lane * 8];
        dst.k2 = *(const s16x8*)&KT[1024 + lane * 8];
        dst.k3 = *(const s16x8*)&KT[1536 + lane * 8];
        const u16* VT = VF + (size_t)(kbn >> 5) * 2048;
        dst.v0 = *(const s16x8*)&VT[lane * 8];
        dst.v1 = *(const s16x8*)&VT[512 + lane * 8];
        dst.v2 = *(const s16x8*)&VT[1024 + lane * 8];
        dst.v3 = *(const s16x8*)&VT[1536 + lane * 8];
    };

    auto stage_bias = [&](int it) {
        int itc = it < NIT ? it : NIT - 1;           // clamped (uniform count)
        int kb2 = k0 + itc * 32;
        float* slot = BsW + (it & 3) * 512;
        #pragma unroll
        for (int j = 0; j < 2; ++j) {
            int sl = j * 64 + lane;
            int row = sl >> 3, q8 = sl & 7;
            int sq = q8 ^ (row & 7);                 // inverse-swizzled source
            gload_lds16(&BrowQ[(size_t)row * SDIM + kb2 + sq * 4],
                        (unsigned char*)slot + j * 1024);
        }
    };

    auto compute = [&](int it, KV& cur) {
        // scalar mask word for this 32-key tile
        u32 mb = mB[__builtin_amdgcn_readfirstlane((k0 + it * 32) >> 5)];
        // QK^T swapped: sc[kt][r] = S[k = 16kt+4g4+r][q = r16]
        f32x4 sc0 = mfma16(cur.k1, qf1, mfma16(cur.k0, qf0, zero4()));
        f32x4 sc1 = mfma16(cur.k3, qf1, mfma16(cur.k2, qf0, zero4()));
        // bias from the LDS ring (swizzled quads)
        float* Bs = BsW + (it & 3) * 512;
        float4 bc0 = *(const float4*)&Bs[r16 * 32 + ((g4 ^ (r16 & 7)) * 4)];
        float4 bc1 = *(const float4*)&Bs[r16 * 32 + (((4 + g4) ^ (r16 & 7)) * 4)];
        sc0[0] += bc0.x; sc0[1] += bc0.y; sc0[2] += bc0.z; sc0[3] += bc0.w;
        sc1[0] += bc1.x; sc1[1] += bc1.y; sc1[2] += bc1.z; sc1[3] += bc1.w;
        // key-padding poison via bitmask
        u32 h0 = mb >> (g4 * 4), h1 = mb >> (16 + g4 * 4);
        #pragma unroll
        for (int r = 0; r < 4; ++r) {
            if ((h0 >> r) & 1) sc0[r] = -1e30f;
            if ((h1 >> r) & 1) sc1[r] = -1e30f;
        }
        // online softmax for column q = r16 (32 keys: 8 in-lane x 4 lane-groups)
        float pm = fmaxf(fmaxf(fmaxf(sc0[0], sc0[1]), fmaxf(sc0[2], sc0[3])),
                         fmaxf(fmaxf(sc1[0], sc1[1]), fmaxf(sc1[2], sc1[3])));
        pm = fmaxf(pm, __shfl_xor(pm, 16));
        pm = fmaxf(pm, __shfl_xor(pm, 32));
        float mn = fmaxf(m_run, pm);
        float alpha = __expf(m_run - mn);
        float p[8];
        #pragma unroll
        for (int r = 0; r < 4; ++r) p[r]     = __expf(sc0[r] - mn);
        #pragma unroll
        for (int r = 0; r < 4; ++r) p[4 + r] = __expf(sc1[r] - mn);
        float ps = ((p[0] + p[1]) + (p[2] + p[3])) + ((p[4] + p[5]) + (p[6] + p[7]));
        ps += __shfl_xor(ps, 16);
        ps += __shfl_xor(ps, 32);
        l_run = l_run * alpha + ps;
        m_run = mn;
        // P -> bf16, packed LDS writes: Pl[q = r16][k = 16kt + 4g4 + 0..3]
        uint2 pv0, pv1;
        pv0.x = (u32)f2b(p[0]) | ((u32)f2b(p[1]) << 16);
        pv0.y = (u32)f2b(p[2]) | ((u32)f2b(p[3]) << 16);
        pv1.x = (u32)f2b(p[4]) | ((u32)f2b(p[5]) << 16);
        pv1.y = (u32)f2b(p[6]) | ((u32)f2b(p[7]) << 16);
        *(uint2*)&Pl[r16 * 40 + g4 * 4]      = pv0;
        *(uint2*)&Pl[r16 * 40 + 16 + g4 * 4] = pv1;
        // alpha (held at lane r16=q) -> row-form q = 4g4+r for the rescale
        float aR0 = __shfl(alpha, g4 * 4 + 0);
        float aR1 = __shfl(alpha, g4 * 4 + 1);
        float aR2 = __shfl(alpha, g4 * 4 + 2);
        float aR3 = __shfl(alpha, g4 * 4 + 3);
        #pragma unroll
        for (int dt = 0; dt < 4; ++dt) {
            accO[dt][0] *= aR0;
            accO[dt][1] *= aR1;
            accO[dt][2] *= aR2;
            accO[dt][3] *= aR3;
        }
        // PV: A = P rows q=r16 (k-slice g4*8), B = V fragments
        s16x8 pf = *(const s16x8*)&Pl[r16 * 40 + g4 * 8];
        accO[0] = mfma16(pf, cur.v0, accO[0]);
        accO[1] = mfma16(pf, cur.v1, accO[1]);
        accO[2] = mfma16(pf, cur.v2, accO[2]);
        accO[3] = mfma16(pf, cur.v3, accO[3]);
    };

    // prologue: kv(0) regs, bias tiles 0,1 staged
    KV A, B;
    issue_kv(0, A);
    stage_bias(0);
    stage_bias(1);

    for (int t = 0; t < NIT; t += 2) {
        issue_kv(t + 1, B);
        stage_bias(t + 2);
        asm volatile("s_waitcnt vmcnt(12)" ::: "memory");
        __builtin_amdgcn_sched_barrier(0);
        compute(t, A);

        issue_kv(t + 2, A);
        stage_bias(t + 3);
        asm volatile("s_waitcnt vmcnt(12)" ::: "memory");
        __builtin_amdgcn_sched_barrier(0);
        compute(t + 1, B);
    }

    // ---- combine the two waves' partials (reuse LDS) ----
    __syncthreads();
    float* As = (float*)SM;                 // [2][16][68]
    float* Ml = (float*)(SM + 8704);        // [2][16]
    float* Ll = Ml + 32;
    #pragma unroll
    for (int dt = 0; dt < 4; ++dt)
        #pragma unroll
        for (int r = 0; r < 4; ++r)
            As[(w * 16 + g4 * 4 + r) * 68 + dt * 16 + r16] = accO[dt][r];
    if (g4 == 0) { Ml[w * 16 + r16] = m_run; Ll[w * 16 + r16] = l_run; }
    __syncthreads();

    #pragma unroll
    for (int half = 0; half < 2; ++half) {
        int d = w * 32 + half * 16 + r16;
        #pragma unroll
        for (int r = 0; r < 4; ++r) {
            int q = g4 * 4 + r;
            float m0 = Ml[q], m1 = Ml[16 + q];
            float mt = fmaxf(m0, m1);
            float e0 = __expf(m0 - mt), e1 = __expf(m1 - mt);
            float lt = Ll[q] * e0 + Ll[16 + q] * e1;
            float o = (As[q * 68 + d] * e0 + As[(16 + q) * 68 + d] * e1) / lt;
            attn_out[((size_t)(qbase + q) * BDIM + b_) * EDIM + h_ * DDIM + d] = f2b(o);
        }
    }
}

extern "C" void kernel_launch(void* const* d_in, const int* in_sizes, int n_in,
                              void* d_out, int out_size, void* d_ws, size_t ws_size,
                              hipStream_t stream) {
    const float* query     = (const float*)d_in[0];
    const float* attn_bias = (const float*)d_in[1];
    const u32*   mask_raw  = (const u32*)d_in[2];
    const float* Wq = (const float*)d_in[3];
    const float* bq = (const float*)d_in[4];
    const float* Wk = (const float*)d_in[5];
    const float* bk = (const float*)d_in[6];
    const float* Wv = (const float*)d_in[7];
    const float* bv = (const float*)d_in[8];
    const float* Wo = (const float*)d_in[9];
    const float* bo = (const float*)d_in[10];
    float* out = (float*)d_out;

    // workspace layout: maskBits(16KB) | qws | kws | vws | aws(=qbf) | 4x Wbf
    char* ws = (char*)d_ws;
    u32* maskB = (u32*)ws;
    const size_t HEADSZ = (size_t)BDIM * HDIM * SDIM * DDIM;  // 3,145,728 elems
    const size_t WSZ = (size_t)EDIM * EDIM;                   //   589,824 elems
    u16* qws = (u16*)(ws + 16384);
    u16* kws = qws + HEADSZ;
    u16* vws = kws + HEADSZ;
    u16* aws = vws + HEADSZ;      // attn out; doubles as bf16 query (qbf)
    u16* qbf = aws;
    u16* wWq = aws + HEADSZ;
    u16* wWk = wWq + WSZ;
    u16* wWv = wWk + WSZ;
    u16* wWo = wWv + WSZ;

    mask_bits_kernel<<<1, 256, 0, stream>>>(mask_raw, maskB);

    // bf16 conversions: query (into qbf=aws region) and the four W matrices
    conv_f32_bf16<<<(int)(MDIM * EDIM / 8 / 256), 256, 0, stream>>>(query, qbf, MDIM * EDIM / 8);
    conv_f32_bf16<<<(int)(WSZ / 8 / 256), 256, 0, stream>>>(Wq, wWq, (int)(WSZ / 8));
    conv_f32_bf16<<<(int)(WSZ / 8 / 256), 256, 0, stream>>>(Wk, wWk, (int)(WSZ / 8));
    conv_f32_bf16<<<(int)(WSZ / 8 / 256), 256, 0, stream>>>(Wv, wWv, (int)(WSZ / 8));
    conv_f32_bf16<<<(int)(WSZ / 8 / 256), 256, 0, stream>>>(Wo, wWo, (int)(WSZ / 8));

    dim3 gg(MDIM / 64, EDIM / 64);
    gemm_xwT<<<gg, 256, 0, stream>>>(qbf, wWq, bq, SCALE_Q, qws, nullptr, 1);
    gemm_xwT<<<gg, 256, 0, stream>>>(qbf, wWk, bk, 1.0f,    kws, nullptr, 3);
    gemm_xwT<<<gg, 256, 0, stream>>>(qbf, wWv, bv, 1.0f,    vws, nullptr, 4);

    dim3 ga(SDIM / 16, BDIM * HDIM);
    attn_fused<<<ga, 128, 0, stream>>>(qws, kws, vws, attn_bias, maskB, aws);

    gemm_xwT<<<gg, 256, 0, stream>>>(aws, wWo, bo, 1.0f, nullptr, out, 0);
}